// Round 19
// baseline (154.250 us; speedup 1.0000x reference)
//
#include <hip/hip_runtime.h>
#include <math.h>
#include <string.h>

#define D 2048
#define NTOK 16384
#define NROW 11
#define MROWS_U32 (NROW * D / 2)   // 11264 uints = 44 KB (packed 2xf16)
#define K1_BLOCKS 1024
#define K1_THREADS 256             // 4 waves; block = 16 tokens, wave = K-quarter
#define WSTRIDE_U 1036             // uints per LDS W row (4144 B; start banks 2-way = free)
#define TILE_S 20                  // f32 stride of C-tile row (80 B, 16B-aligned)

// ws layout (4-byte units):
// [0..10] a_k  [16..26] b_k  [32] inv_temp  [33] alpha  [34..36] mix
// [40..63] M3 (8x3)  [64 .. 64+11264) packed-f16 W'  [WS_PART..) partials [67][1024]
// [WS_CTR] completion counter (uint)
#define WS_A 0
#define WS_B 16
#define WS_IT 32
#define WS_ALPHA 33
#define WS_MIX 34
#define WS_M3 40
#define WS_MERGED 64
#define WS_PART (WS_MERGED + MROWS_U32)
#define WS_CTR (WS_PART + 67 * K1_BLOCKS)

typedef __fp16 h2 __attribute__((ext_vector_type(2)));
typedef __fp16 h8 __attribute__((ext_vector_type(8)));
typedef float f32x4 __attribute__((ext_vector_type(4)));

__device__ __forceinline__ float wsum(float v){
#pragma unroll
  for (int m = 1; m < 64; m <<= 1) v += __shfl_xor(v, m, 64);
  return v;
}
__device__ __forceinline__ float wmax(float v){
#pragma unroll
  for (int m = 1; m < 64; m <<= 1) v = fmaxf(v, __shfl_xor(v, m, 64));
  return v;
}
__device__ __forceinline__ float rcp_fast(float x){ return __builtin_amdgcn_rcpf(x); }
__device__ __forceinline__ float tanh_fast(float x){
  float e = __expf(2.0f * x);
  return 1.0f - 2.0f * rcp_fast(e + 1.0f);
}
__device__ __forceinline__ float sload(const float* __restrict__ p){
  return __uint_as_float(__builtin_amdgcn_readfirstlane(__float_as_uint(*p)));
}
__device__ __forceinline__ unsigned int h2u(h2 h){ unsigned int u; memcpy(&u, &h, 4); return u; }

// ---------------- k0: merge rows (f16-packed) + constants + zero ctr ----------------
__global__ __launch_bounds__(256) void k0_prep(
    const float* __restrict__ ln_w, const float* __restrict__ ln_b,
    const float* __restrict__ w_q2, const float* __restrict__ w_q3,
    const float* __restrict__ w_q6,
    const float* __restrict__ log_temp, const float* __restrict__ log_scale_mix,
    const float* __restrict__ q3_to_group, const float* __restrict__ log_wht_mix,
    float* __restrict__ ws)
{
  const int tid = threadIdx.x;
  const int k = blockIdx.x;
  unsigned int* wsu = (unsigned int*)ws;
  if (k < NROW){
    const float* row = (k < 2) ? (w_q2 + (size_t)k * D)
                     : (k < 5) ? (w_q3 + (size_t)(k - 2) * D)
                               : (w_q6 + (size_t)(k - 5) * D);
    float pa = 0.f, pb = 0.f;
    for (int i = tid * 2; i < D; i += 512){
      float w0 = row[i], w1 = row[i + 1];
      h2 h = __builtin_amdgcn_cvt_pkrtz(ln_w[i] * w0, ln_w[i + 1] * w1);
      pa += (float)h[0] + (float)h[1];          // a_k from ROUNDED values
      pb = fmaf(ln_b[i], w0, pb);
      pb = fmaf(ln_b[i + 1], w1, pb);
      wsu[WS_MERGED + k * 1024 + i / 2] = h2u(h);
    }
    __shared__ float red[8];
    pa = wsum(pa); pb = wsum(pb);
    if ((tid & 63) == 0){ red[tid >> 6] = pa; red[4 + (tid >> 6)] = pb; }
    __syncthreads();
    if (tid == 0){
      ws[WS_A + k] = red[0] + red[1] + red[2] + red[3];
      ws[WS_B + k] = red[4] + red[5] + red[6] + red[7];
    }
  } else if (tid < 64){
    // block 11: constants, lane-parallel
    const int lane = tid;
    float q3v = (lane < 24) ? q3_to_group[lane]   : 0.f;
    float sc  = (lane < 3)  ? log_scale_mix[lane] : 0.f;
    float lt  = (lane == 0) ? log_temp[0]         : 0.f;
    float lw  = (lane == 0) ? log_wht_mix[0]      : 0.f;

    if (lane == 0){
      float t = __expf(lt);
      t = fminf(fmaxf(t, 0.1f), 5.0f);
      ws[WS_IT] = 1.0f / t;
      ws[WS_ALPHA] = 1.0f / (1.0f + __expf(-lw));
    }
    float m0 = __shfl(sc, 0, 64), m1 = __shfl(sc, 1, 64), m2 = __shfl(sc, 2, 64);
    if (lane < 3){
      float mm = fmaxf(m0, fmaxf(m1, m2));
      float e0 = __expf(m0 - mm), e1 = __expf(m1 - mm), e2 = __expf(m2 - mm);
      float inv = 1.0f / (e0 + e1 + e2);
      ws[WS_MIX + lane] = ((lane == 0) ? e0 : (lane == 1) ? e1 : e2) * inv;
    }
    if (lane < 24){
      int r = lane / 3, c = lane - r * 3;
      float v0 = __shfl(q3v, r*3 + 0, 64);
      float v1 = __shfl(q3v, r*3 + 1, 64);
      float v2 = __shfl(q3v, r*3 + 2, 64);
      float mx = fmaxf(v0, fmaxf(v1, v2));
      float f0 = __expf(v0 - mx), f1 = __expf(v1 - mx), f2 = __expf(v2 - mx);
      float iv = 1.0f / (f0 + f1 + f2);
      ws[WS_M3 + lane] = ((c == 0) ? f0 : (c == 1) ? f1 : f2) * iv;
    }
  } else if (tid == 64){
    // zero the completion counter every launch (replay-deterministic)
    wsu[WS_CTR] = 0u;
  }
}

// ---------------- k1: MFMA per-token kernel + fused final reduction ----------------
// 1024 blocks x 256 threads (4 waves). Block = 16 tokens, wave = K-quarter:
// 16x v_mfma_f32_16x16x32_f16 into a 16x16 C tile. Batch-2 x loads issued
// AFTER the barrier so K-loop part 1 covers their latency. Epilogue fully
// unrolled (round 16). The LAST block (device-scope counter election) runs
// the 67-row partial reduction + lb_loss inline -- no separate k2 dispatch.
__global__ __launch_bounds__(256) void k1_main(
    const float* __restrict__ x, const float* __restrict__ ws,
    float* __restrict__ gout, float* __restrict__ hout,
    float* __restrict__ part, unsigned int* __restrict__ ctr,
    float* __restrict__ lout)
{
  __shared__ unsigned int sW[NROW * WSTRIDE_U];    // 45.6 KB
  __shared__ float tile[4][16][TILE_S];            // 5.1 KB
  __shared__ float lred[4][68];
  __shared__ float sums[68];
  __shared__ unsigned int is_last_s;
  const int tid  = threadIdx.x;
  const int lane = tid & 63;
  const int wid  = tid >> 6;          // K-quarter
  const int blk  = blockIdx.x;
  const int tok0 = blk * 16;
  const int n = lane & 15;            // A-row (token) / B-col (W row)
  const int q = lane >> 4;            // K-chunk within step

  const float* xp = x + (size_t)(tok0 + n) * D + wid * 512 + q * 8;

  // ---- issue batch-1 loads (steps 0..7) ----
  float4 xa[16];
#pragma unroll
  for (int s = 0; s < 8; ++s){
    xa[2*s]     = *(const float4*)(xp + s * 32);
    xa[2*s + 1] = *(const float4*)(xp + s * 32 + 4);
  }

  // ---- stage W' (11 rows, stride 1036 u) -- covers batch-1 latency ----
  {
    const uint4* src = (const uint4*)((const unsigned int*)ws + WS_MERGED);
#pragma unroll
    for (int j = 0; j < 11; ++j){
      int idx = tid + j * 256;
      int r = idx >> 8, i = idx & 255;
      *(uint4*)(sW + r * WSTRIDE_U + i * 4) = src[r * 256 + i];
    }
  }

  // ---- convert batch 1 -> h8 frags + sq ----
  float sq = 0.f;
  h8 hxA[8], hxB[8];
#pragma unroll
  for (int s = 0; s < 8; ++s){
    float4 f0 = xa[2*s], f1 = xa[2*s + 1];
    sq = fmaf(f0.x,f0.x, fmaf(f0.y,f0.y, fmaf(f0.z,f0.z, fmaf(f0.w,f0.w, sq))));
    sq = fmaf(f1.x,f1.x, fmaf(f1.y,f1.y, fmaf(f1.z,f1.z, fmaf(f1.w,f1.w, sq))));
    h2 p0 = __builtin_amdgcn_cvt_pkrtz(f0.x, f0.y);
    h2 p1 = __builtin_amdgcn_cvt_pkrtz(f0.z, f0.w);
    h2 p2 = __builtin_amdgcn_cvt_pkrtz(f1.x, f1.y);
    h2 p3 = __builtin_amdgcn_cvt_pkrtz(f1.z, f1.w);
    h8 A;
    A[0]=p0[0]; A[1]=p0[1]; A[2]=p1[0]; A[3]=p1[1];
    A[4]=p2[0]; A[5]=p2[1]; A[6]=p3[0]; A[7]=p3[1];
    hxA[s] = A;
  }

  __syncthreads();   // W' staged

  // ---- issue batch-2 loads AFTER barrier: K-loop part 1 covers latency ----
#pragma unroll
  for (int s = 0; s < 8; ++s){
    xa[2*s]     = *(const float4*)(xp + (s + 8) * 32);
    xa[2*s + 1] = *(const float4*)(xp + (s + 8) * 32 + 4);
  }

  const int wr = (n < NROW) ? n : (n - NROW);
  const bool is_ones = (n == NROW);
  const uint4 ones4 = make_uint4(0x3C003C00u, 0x3C003C00u, 0x3C003C00u, 0x3C003C00u);
  const unsigned int* wb = sW + wr * WSTRIDE_U + wid * 256 + q * 4;

  f32x4 acc = {0.f, 0.f, 0.f, 0.f};

#pragma unroll
  for (int s = 0; s < 8; ++s){
    uint4 wq = *(const uint4*)(wb + s * 16);
    if (is_ones) wq = ones4;
    h8 B; memcpy(&B, &wq, 16);
    acc = __builtin_amdgcn_mfma_f32_16x16x32_f16(hxA[s], B, acc, 0, 0, 0);
  }

#pragma unroll
  for (int s = 0; s < 8; ++s){
    float4 f0 = xa[2*s], f1 = xa[2*s + 1];
    sq = fmaf(f0.x,f0.x, fmaf(f0.y,f0.y, fmaf(f0.z,f0.z, fmaf(f0.w,f0.w, sq))));
    sq = fmaf(f1.x,f1.x, fmaf(f1.y,f1.y, fmaf(f1.z,f1.z, fmaf(f1.w,f1.w, sq))));
    h2 p0 = __builtin_amdgcn_cvt_pkrtz(f0.x, f0.y);
    h2 p1 = __builtin_amdgcn_cvt_pkrtz(f0.z, f0.w);
    h2 p2 = __builtin_amdgcn_cvt_pkrtz(f1.x, f1.y);
    h2 p3 = __builtin_amdgcn_cvt_pkrtz(f1.z, f1.w);
    h8 A;
    A[0]=p0[0]; A[1]=p0[1]; A[2]=p1[0]; A[3]=p1[1];
    A[4]=p2[0]; A[5]=p2[1]; A[6]=p3[0]; A[7]=p3[1];
    hxB[s] = A;
  }

#pragma unroll
  for (int s = 0; s < 8; ++s){
    uint4 wq = *(const uint4*)(wb + (s + 8) * 16);
    if (is_ones) wq = ones4;
    h8 B; memcpy(&B, &wq, 16);
    acc = __builtin_amdgcn_mfma_f32_16x16x32_f16(hxB[s], B, acc, 0, 0, 0);
  }

  // sq: reduce over the 4 K-chunk lanes of token n
  sq += __shfl_xor(sq, 16, 64);
  sq += __shfl_xor(sq, 32, 64);

  // C layout (m89): token = q*4 + r, output col = n
#pragma unroll
  for (int r = 0; r < 4; ++r) tile[wid][q * 4 + r][n] = acc[r];
  if (lane < 16) tile[wid][lane][16] = sq;

  __syncthreads();

  // uniform constants -> SGPRs
  float a[NROW], bb[NROW];
#pragma unroll
  for (int k = 0; k < NROW; ++k){ a[k] = sload(ws + WS_A + k); bb[k] = sload(ws + WS_B + k); }
  const float it    = sload(ws + WS_IT);
  const float alpha = sload(ws + WS_ALPHA);
  const float mix0 = sload(ws + WS_MIX), mix1 = sload(ws + WS_MIX + 1), mix2 = sload(ws + WS_MIX + 2);
  float M3r[8][3];
#pragma unroll
  for (int r = 0; r < 8; ++r){
#pragma unroll
    for (int g2 = 0; g2 < 3; ++g2) M3r[r][g2] = sload(ws + WS_M3 + r*3 + g2);
  }

  // per-lane hexagram row constants
  float sgn[6];
#pragma unroll
  for (int j = 0; j < 6; ++j) sgn[j] = ((lane >> (5 - j)) & 1) ? 1.0f : -1.0f;
  const float C5 = 0.44721359549995793f; // 1/sqrt(5)
  const float A0c[6] = { C5,  C5,  C5,  C5,  C5, 0.f };
  const float A1c[6] = {-0.5f, 0.5f, -0.5f, 0.f, 0.f, 0.5f};
  const float A2c[6] = {-C5, -C5, 0.f, -C5, -C5, -C5};
  float cs0 = 0.f, cs1 = 0.f, cs2 = 0.f;
#pragma unroll
  for (int j = 0; j < 6; ++j){
    cs0 = fmaf(sgn[j], A0c[j], cs0);
    cs1 = fmaf(sgn[j], A1c[j], cs1);
    cs2 = fmaf(sgn[j], A2c[j], cs2);
  }
  const int pc = __popc(lane);
  const float w7c = 1.0f / 7.0f;
  float wh0 = (pc >= 5) ? w7c  : 0.f;
  float wh1 = (pc == 3) ? 0.05f: 0.f;
  float wh2 = (pc <= 1) ? w7c  : 0.f;
  const float m60 = (1.f - alpha)*cs0 + alpha*wh0;
  const float m61 = (1.f - alpha)*cs1 + alpha*wh1;
  const float m62 = (1.f - alpha)*cs2 + alpha*wh2;

  float hsum = 0.f, ga0 = 0.f, ga1 = 0.f, ga2 = 0.f;

  // epilogue: wave wid handles local tokens wid*4 .. wid*4+3, fully unrolled
#pragma unroll
  for (int i = 0; i < 4; ++i){
    const int tl  = wid * 4 + i;
    const int tok = tok0 + tl;

    float t[12]; float sqv = 0.f;
#pragma unroll
    for (int k = 0; k < 12; ++k) t[k] = 0.f;
#pragma unroll
    for (int hh = 0; hh < 4; ++hh){
      const float* row = &tile[hh][tl][0];
      float4 c0 = *(const float4*)(row);
      float4 c1 = *(const float4*)(row + 4);
      float4 c2 = *(const float4*)(row + 8);
      t[0] += c0.x; t[1] += c0.y; t[2]  += c0.z; t[3]  += c0.w;
      t[4] += c1.x; t[5] += c1.y; t[6]  += c1.z; t[7]  += c1.w;
      t[8] += c2.x; t[9] += c2.y; t[10] += c2.z; t[11] += c2.w;
      sqv += row[16];
    }

    float mean = t[11] * (1.0f / D);
    float var  = fmaf(sqv, 1.0f / D, -mean * mean);
    float rr   = rsqrtf(var + 1e-5f);
    float u[NROW];
#pragma unroll
    for (int k = 0; k < NROW; ++k){
      float d = fmaf(-mean, a[k], t[k]);
      u[k] = tanh_fast(fmaf(rr, d, bb[k]));
    }

    // ---- Q2 ----
    float p01 = u[0] + u[1], m01 = u[0] - u[1];
    float l0 = -p01*it, l1 = -m01*it, l2 = m01*it, l3 = p01*it;
    float mx2 = fmaxf(fmaxf(l0, l1), fmaxf(l2, l3));
    float e0 = __expf(l0-mx2), e1 = __expf(l1-mx2), e2 = __expf(l2-mx2), e3 = __expf(l3-mx2);
    float i2 = rcp_fast(e0 + e1 + e2 + e3);
    float s2g0 = e3 * i2, s2g1 = (e1 + e2) * i2, s2g2 = e0 * i2;

    // ---- Q3 ----
    float l3v[8]; float mx3 = -1e30f;
#pragma unroll
    for (int v = 0; v < 8; ++v){
      float acc3 = ((v & 4) ? u[2] : -u[2]) + ((v & 2) ? u[3] : -u[3]) + ((v & 1) ? u[4] : -u[4]);
      l3v[v] = acc3 * it;
      mx3 = fmaxf(mx3, l3v[v]);
    }
    float w3v[8]; float se3 = 0.f;
#pragma unroll
    for (int v = 0; v < 8; ++v){ w3v[v] = __expf(l3v[v] - mx3); se3 += w3v[v]; }
    float i3 = rcp_fast(se3);
    float s3g0 = 0.f, s3g1 = 0.f, s3g2 = 0.f;
#pragma unroll
    for (int v = 0; v < 8; ++v){
      s3g0 = fmaf(w3v[v], M3r[v][0], s3g0);
      s3g1 = fmaf(w3v[v], M3r[v][1], s3g1);
      s3g2 = fmaf(w3v[v], M3r[v][2], s3g2);
    }
    s3g0 *= i3; s3g1 *= i3; s3g2 *= i3;

    // ---- Q6 (lane-parallel over 64 vertices) ----
    float lg = 0.f;
#pragma unroll
    for (int jj = 0; jj < 6; ++jj) lg = fmaf(sgn[jj], u[5 + jj], lg);
    lg *= it;
    float mx6 = wmax(lg);
    float p   = __expf(lg - mx6);
    float se6 = wsum(p);
    float hw  = p * rcp_fast(se6);
    hout[(size_t)tok * 64 + lane] = hw;
    hsum += hw;
    float s6g0 = wsum(hw * m60);
    float s6g1 = wsum(hw * m61);
    float s6g2 = wsum(hw * m62);

    // ---- combine + group softmax ----
    float g0 = mix0*s2g0 + mix1*s3g0 + mix2*s6g0;
    float g1 = mix0*s2g1 + mix1*s3g1 + mix2*s6g1;
    float g2 = mix0*s2g2 + mix1*s3g2 + mix2*s6g2;
    float gm = fmaxf(g0, fmaxf(g1, g2));
    float y0 = __expf(g0-gm), y1 = __expf(g1-gm), y2 = __expf(g2-gm);
    float gi = rcp_fast(y0 + y1 + y2);
    float gw0 = y0*gi, gw1 = y1*gi, gw2 = y2*gi;
    ga0 += gw0; ga1 += gw1; ga2 += gw2;
    if (lane < 3){
      float val = (lane == 0) ? gw0 : (lane == 1) ? gw1 : gw2;
      gout[(size_t)tok * 3 + lane] = val;
    }
  }

  // contention-free block partials for lb_loss
  lred[wid][lane] = hsum;
  if (lane < 3){
    float val = (lane == 0) ? ga0 : (lane == 1) ? ga1 : ga2;
    lred[wid][64 + lane] = val;
  }
  __syncthreads();
  if (tid < 67){
    float v = lred[0][tid] + lred[1][tid] + lred[2][tid] + lred[3][tid];
    part[(size_t)tid * K1_BLOCKS + blk] = v;
  }

  // ---- last-block election (device-scope fence + counter) ----
  __threadfence();            // release: publish part writes
  __syncthreads();
  if (tid == 0){
    unsigned int old = atomicAdd(ctr, 1u);
    if (old == K1_BLOCKS - 1){
      __threadfence();        // acquire: invalidate caches before reading parts
      is_last_s = 1u;
    } else {
      is_last_s = 0u;
    }
  }
  __syncthreads();
  if (!is_last_s) return;

  // ---- fused final reduction + lb_loss (runs on exactly one block) ----
  for (int jv = wid; jv < 67; jv += 4){
    const float4* p = (const float4*)(part + (size_t)jv * K1_BLOCKS);
    float v = 0.f;
#pragma unroll
    for (int b = 0; b < K1_BLOCKS / 256; ++b){
      float4 qq = p[lane + b * 64];
      v += (qq.x + qq.y) + (qq.z + qq.w);
    }
    v = wsum(v);
    if (lane == 0) sums[jv] = v;
  }
  __syncthreads();
  if (wid == 0){
    const float inv = 1.0f / (float)NTOK;
    float mh = sums[lane] * inv;
    float term = 0.1f * mh * logf(mh + 1e-8f);
    if (lane < 3){
      float mg = sums[64 + lane] * inv;
      term += mg * logf(mg + 1e-8f);
    }
    float L = wsum(term);
    if (lane == 0) lout[0] = L;
  }
}

extern "C" void kernel_launch(void* const* d_in, const int* in_sizes, int n_in,
                              void* d_out, int out_size, void* d_ws, size_t ws_size,
                              hipStream_t stream)
{
  const float* x             = (const float*)d_in[0];
  const float* ln_w          = (const float*)d_in[1];
  const float* ln_b          = (const float*)d_in[2];
  const float* w_q2          = (const float*)d_in[3];
  const float* w_q3          = (const float*)d_in[4];
  const float* w_q6          = (const float*)d_in[5];
  const float* log_temp      = (const float*)d_in[6];
  const float* log_scale_mix = (const float*)d_in[7];
  const float* q3_to_group   = (const float*)d_in[8];
  const float* log_wht_mix   = (const float*)d_in[9];

  float* out  = (float*)d_out;
  float* gout = out;                                        // (B,T,3)
  float* hout = out + (size_t)NTOK * 3;                     // (B,T,64)
  float* lout = out + (size_t)NTOK * 3 + (size_t)NTOK * 64; // scalar
  float* ws   = (float*)d_ws;
  unsigned int* ctr = (unsigned int*)ws + WS_CTR;

  k0_prep<<<12, 256, 0, stream>>>(ln_w, ln_b, w_q2, w_q3, w_q6,
                                  log_temp, log_scale_mix, q3_to_group, log_wht_mix, ws);
  k1_main<<<K1_BLOCKS, K1_THREADS, 0, stream>>>(x, ws, gout, hout,
                                                ws + WS_PART, ctr, lout);
}

// Round 20
// 154.077 us; speedup vs baseline: 1.0011x; 1.0011x over previous
//
#include <hip/hip_runtime.h>
#include <math.h>
#include <string.h>

#define D 2048
#define NTOK 16384
#define NROW 11
#define MROWS_U32 (NROW * D / 2)   // 11264 uints = 44 KB (packed 2xf16)
#define K1_BLOCKS 1024
#define K1_THREADS 256             // 4 waves; block = 16 tokens, wave = K-quarter
#define WSTRIDE_U 1036             // uints per LDS W row (4144 B; start banks 2-way = free)
#define TILE_S 20                  // f32 stride of C-tile row (80 B, 16B-aligned)

// ws layout (4-byte units):
// [0..10] a_k  [16..26] b_k  [32] inv_temp  [33] alpha  [34..36] mix
// [40..63] M3 (8x3)  [64 .. 64+11264) packed-f16 W'  [WS_PART..) partials [67][1024]
// [WS_CTR] completion counter (uint)
#define WS_A 0
#define WS_B 16
#define WS_IT 32
#define WS_ALPHA 33
#define WS_MIX 34
#define WS_M3 40
#define WS_MERGED 64
#define WS_PART (WS_MERGED + MROWS_U32)
#define WS_CTR (WS_PART + 67 * K1_BLOCKS)

typedef __fp16 h2 __attribute__((ext_vector_type(2)));
typedef __fp16 h8 __attribute__((ext_vector_type(8)));
typedef float f32x4 __attribute__((ext_vector_type(4)));

__device__ __forceinline__ float wsum(float v){
#pragma unroll
  for (int m = 1; m < 64; m <<= 1) v += __shfl_xor(v, m, 64);
  return v;
}
__device__ __forceinline__ float wmax(float v){
#pragma unroll
  for (int m = 1; m < 64; m <<= 1) v = fmaxf(v, __shfl_xor(v, m, 64));
  return v;
}
__device__ __forceinline__ float rcp_fast(float x){ return __builtin_amdgcn_rcpf(x); }
__device__ __forceinline__ float tanh_fast(float x){
  float e = __expf(2.0f * x);
  return 1.0f - 2.0f * rcp_fast(e + 1.0f);
}
__device__ __forceinline__ float sload(const float* __restrict__ p){
  return __uint_as_float(__builtin_amdgcn_readfirstlane(__float_as_uint(*p)));
}
__device__ __forceinline__ unsigned int h2u(h2 h){ unsigned int u; memcpy(&u, &h, 4); return u; }

// ---------------- k0: merge rows (f16-packed) + constants + zero ctr ----------------
__global__ __launch_bounds__(256) void k0_prep(
    const float* __restrict__ ln_w, const float* __restrict__ ln_b,
    const float* __restrict__ w_q2, const float* __restrict__ w_q3,
    const float* __restrict__ w_q6,
    const float* __restrict__ log_temp, const float* __restrict__ log_scale_mix,
    const float* __restrict__ q3_to_group, const float* __restrict__ log_wht_mix,
    float* __restrict__ ws)
{
  const int tid = threadIdx.x;
  const int k = blockIdx.x;
  unsigned int* wsu = (unsigned int*)ws;
  if (k < NROW){
    const float* row = (k < 2) ? (w_q2 + (size_t)k * D)
                     : (k < 5) ? (w_q3 + (size_t)(k - 2) * D)
                               : (w_q6 + (size_t)(k - 5) * D);
    float pa = 0.f, pb = 0.f;
    for (int i = tid * 2; i < D; i += 512){
      float w0 = row[i], w1 = row[i + 1];
      h2 h = __builtin_amdgcn_cvt_pkrtz(ln_w[i] * w0, ln_w[i + 1] * w1);
      pa += (float)h[0] + (float)h[1];          // a_k from ROUNDED values
      pb = fmaf(ln_b[i], w0, pb);
      pb = fmaf(ln_b[i + 1], w1, pb);
      wsu[WS_MERGED + k * 1024 + i / 2] = h2u(h);
    }
    __shared__ float red[8];
    pa = wsum(pa); pb = wsum(pb);
    if ((tid & 63) == 0){ red[tid >> 6] = pa; red[4 + (tid >> 6)] = pb; }
    __syncthreads();
    if (tid == 0){
      ws[WS_A + k] = red[0] + red[1] + red[2] + red[3];
      ws[WS_B + k] = red[4] + red[5] + red[6] + red[7];
    }
  } else if (tid < 64){
    // block 11: constants, lane-parallel
    const int lane = tid;
    float q3v = (lane < 24) ? q3_to_group[lane]   : 0.f;
    float sc  = (lane < 3)  ? log_scale_mix[lane] : 0.f;
    float lt  = (lane == 0) ? log_temp[0]         : 0.f;
    float lw  = (lane == 0) ? log_wht_mix[0]      : 0.f;

    if (lane == 0){
      float t = __expf(lt);
      t = fminf(fmaxf(t, 0.1f), 5.0f);
      ws[WS_IT] = 1.0f / t;
      ws[WS_ALPHA] = 1.0f / (1.0f + __expf(-lw));
    }
    float m0 = __shfl(sc, 0, 64), m1 = __shfl(sc, 1, 64), m2 = __shfl(sc, 2, 64);
    if (lane < 3){
      float mm = fmaxf(m0, fmaxf(m1, m2));
      float e0 = __expf(m0 - mm), e1 = __expf(m1 - mm), e2 = __expf(m2 - mm);
      float inv = 1.0f / (e0 + e1 + e2);
      ws[WS_MIX + lane] = ((lane == 0) ? e0 : (lane == 1) ? e1 : e2) * inv;
    }
    if (lane < 24){
      int r = lane / 3, c = lane - r * 3;
      float v0 = __shfl(q3v, r*3 + 0, 64);
      float v1 = __shfl(q3v, r*3 + 1, 64);
      float v2 = __shfl(q3v, r*3 + 2, 64);
      float mx = fmaxf(v0, fmaxf(v1, v2));
      float f0 = __expf(v0 - mx), f1 = __expf(v1 - mx), f2 = __expf(v2 - mx);
      float iv = 1.0f / (f0 + f1 + f2);
      ws[WS_M3 + lane] = ((c == 0) ? f0 : (c == 1) ? f1 : f2) * iv;
    }
  } else if (tid == 64){
    // zero the completion counter every launch (replay-deterministic)
    wsu[WS_CTR] = 0u;
  }
}

// ---------------- k1: MFMA per-token kernel + fused final reduction ----------------
// 1024 blocks x 256 threads (4 waves). Block = 16 tokens, wave = K-quarter:
// 16x v_mfma_f32_16x16x32_f16 into a 16x16 C tile. Batch-2 x loads issued
// AFTER the barrier so K-loop part 1 covers their latency. Epilogue fully
// unrolled (round 16). The LAST block (device-scope counter election) runs
// the 67-row partial reduction + lb_loss inline -- no separate k2 dispatch.
__global__ __launch_bounds__(256) void k1_main(
    const float* __restrict__ x, const float* __restrict__ ws,
    float* __restrict__ gout, float* __restrict__ hout,
    float* __restrict__ part, unsigned int* __restrict__ ctr,
    float* __restrict__ lout)
{
  __shared__ unsigned int sW[NROW * WSTRIDE_U];    // 45.6 KB
  __shared__ float tile[4][16][TILE_S];            // 5.1 KB
  __shared__ float lred[4][68];
  __shared__ float sums[68];
  __shared__ unsigned int is_last_s;
  const int tid  = threadIdx.x;
  const int lane = tid & 63;
  const int wid  = tid >> 6;          // K-quarter
  const int blk  = blockIdx.x;
  const int tok0 = blk * 16;
  const int n = lane & 15;            // A-row (token) / B-col (W row)
  const int q = lane >> 4;            // K-chunk within step

  const float* xp = x + (size_t)(tok0 + n) * D + wid * 512 + q * 8;

  // ---- issue batch-1 loads (steps 0..7) ----
  float4 xa[16];
#pragma unroll
  for (int s = 0; s < 8; ++s){
    xa[2*s]     = *(const float4*)(xp + s * 32);
    xa[2*s + 1] = *(const float4*)(xp + s * 32 + 4);
  }

  // ---- stage W' (11 rows, stride 1036 u) -- covers batch-1 latency ----
  {
    const uint4* src = (const uint4*)((const unsigned int*)ws + WS_MERGED);
#pragma unroll
    for (int j = 0; j < 11; ++j){
      int idx = tid + j * 256;
      int r = idx >> 8, i = idx & 255;
      *(uint4*)(sW + r * WSTRIDE_U + i * 4) = src[r * 256 + i];
    }
  }

  // ---- convert batch 1 -> h8 frags + sq ----
  float sq = 0.f;
  h8 hxA[8], hxB[8];
#pragma unroll
  for (int s = 0; s < 8; ++s){
    float4 f0 = xa[2*s], f1 = xa[2*s + 1];
    sq = fmaf(f0.x,f0.x, fmaf(f0.y,f0.y, fmaf(f0.z,f0.z, fmaf(f0.w,f0.w, sq))));
    sq = fmaf(f1.x,f1.x, fmaf(f1.y,f1.y, fmaf(f1.z,f1.z, fmaf(f1.w,f1.w, sq))));
    h2 p0 = __builtin_amdgcn_cvt_pkrtz(f0.x, f0.y);
    h2 p1 = __builtin_amdgcn_cvt_pkrtz(f0.z, f0.w);
    h2 p2 = __builtin_amdgcn_cvt_pkrtz(f1.x, f1.y);
    h2 p3 = __builtin_amdgcn_cvt_pkrtz(f1.z, f1.w);
    h8 A;
    A[0]=p0[0]; A[1]=p0[1]; A[2]=p1[0]; A[3]=p1[1];
    A[4]=p2[0]; A[5]=p2[1]; A[6]=p3[0]; A[7]=p3[1];
    hxA[s] = A;
  }

  __syncthreads();   // W' staged

  // ---- issue batch-2 loads AFTER barrier: K-loop part 1 covers latency ----
#pragma unroll
  for (int s = 0; s < 8; ++s){
    xa[2*s]     = *(const float4*)(xp + (s + 8) * 32);
    xa[2*s + 1] = *(const float4*)(xp + (s + 8) * 32 + 4);
  }

  const int wr = (n < NROW) ? n : (n - NROW);
  const bool is_ones = (n == NROW);
  const uint4 ones4 = make_uint4(0x3C003C00u, 0x3C003C00u, 0x3C003C00u, 0x3C003C00u);
  const unsigned int* wb = sW + wr * WSTRIDE_U + wid * 256 + q * 4;

  f32x4 acc = {0.f, 0.f, 0.f, 0.f};

#pragma unroll
  for (int s = 0; s < 8; ++s){
    uint4 wq = *(const uint4*)(wb + s * 16);
    if (is_ones) wq = ones4;
    h8 B; memcpy(&B, &wq, 16);
    acc = __builtin_amdgcn_mfma_f32_16x16x32_f16(hxA[s], B, acc, 0, 0, 0);
  }

#pragma unroll
  for (int s = 0; s < 8; ++s){
    float4 f0 = xa[2*s], f1 = xa[2*s + 1];
    sq = fmaf(f0.x,f0.x, fmaf(f0.y,f0.y, fmaf(f0.z,f0.z, fmaf(f0.w,f0.w, sq))));
    sq = fmaf(f1.x,f1.x, fmaf(f1.y,f1.y, fmaf(f1.z,f1.z, fmaf(f1.w,f1.w, sq))));
    h2 p0 = __builtin_amdgcn_cvt_pkrtz(f0.x, f0.y);
    h2 p1 = __builtin_amdgcn_cvt_pkrtz(f0.z, f0.w);
    h2 p2 = __builtin_amdgcn_cvt_pkrtz(f1.x, f1.y);
    h2 p3 = __builtin_amdgcn_cvt_pkrtz(f1.z, f1.w);
    h8 A;
    A[0]=p0[0]; A[1]=p0[1]; A[2]=p1[0]; A[3]=p1[1];
    A[4]=p2[0]; A[5]=p2[1]; A[6]=p3[0]; A[7]=p3[1];
    hxB[s] = A;
  }

#pragma unroll
  for (int s = 0; s < 8; ++s){
    uint4 wq = *(const uint4*)(wb + (s + 8) * 16);
    if (is_ones) wq = ones4;
    h8 B; memcpy(&B, &wq, 16);
    acc = __builtin_amdgcn_mfma_f32_16x16x32_f16(hxB[s], B, acc, 0, 0, 0);
  }

  // sq: reduce over the 4 K-chunk lanes of token n
  sq += __shfl_xor(sq, 16, 64);
  sq += __shfl_xor(sq, 32, 64);

  // C layout (m89): token = q*4 + r, output col = n
#pragma unroll
  for (int r = 0; r < 4; ++r) tile[wid][q * 4 + r][n] = acc[r];
  if (lane < 16) tile[wid][lane][16] = sq;

  __syncthreads();

  // uniform constants -> SGPRs
  float a[NROW], bb[NROW];
#pragma unroll
  for (int k = 0; k < NROW; ++k){ a[k] = sload(ws + WS_A + k); bb[k] = sload(ws + WS_B + k); }
  const float it    = sload(ws + WS_IT);
  const float alpha = sload(ws + WS_ALPHA);
  const float mix0 = sload(ws + WS_MIX), mix1 = sload(ws + WS_MIX + 1), mix2 = sload(ws + WS_MIX + 2);
  float M3r[8][3];
#pragma unroll
  for (int r = 0; r < 8; ++r){
#pragma unroll
    for (int g2 = 0; g2 < 3; ++g2) M3r[r][g2] = sload(ws + WS_M3 + r*3 + g2);
  }

  // per-lane hexagram row constants
  float sgn[6];
#pragma unroll
  for (int j = 0; j < 6; ++j) sgn[j] = ((lane >> (5 - j)) & 1) ? 1.0f : -1.0f;
  const float C5 = 0.44721359549995793f; // 1/sqrt(5)
  const float A0c[6] = { C5,  C5,  C5,  C5,  C5, 0.f };
  const float A1c[6] = {-0.5f, 0.5f, -0.5f, 0.f, 0.f, 0.5f};
  const float A2c[6] = {-C5, -C5, 0.f, -C5, -C5, -C5};
  float cs0 = 0.f, cs1 = 0.f, cs2 = 0.f;
#pragma unroll
  for (int j = 0; j < 6; ++j){
    cs0 = fmaf(sgn[j], A0c[j], cs0);
    cs1 = fmaf(sgn[j], A1c[j], cs1);
    cs2 = fmaf(sgn[j], A2c[j], cs2);
  }
  const int pc = __popc(lane);
  const float w7c = 1.0f / 7.0f;
  float wh0 = (pc >= 5) ? w7c  : 0.f;
  float wh1 = (pc == 3) ? 0.05f: 0.f;
  float wh2 = (pc <= 1) ? w7c  : 0.f;
  const float m60 = (1.f - alpha)*cs0 + alpha*wh0;
  const float m61 = (1.f - alpha)*cs1 + alpha*wh1;
  const float m62 = (1.f - alpha)*cs2 + alpha*wh2;

  float hsum = 0.f, ga0 = 0.f, ga1 = 0.f, ga2 = 0.f;

  // epilogue: wave wid handles local tokens wid*4 .. wid*4+3, fully unrolled
#pragma unroll
  for (int i = 0; i < 4; ++i){
    const int tl  = wid * 4 + i;
    const int tok = tok0 + tl;

    float t[12]; float sqv = 0.f;
#pragma unroll
    for (int k = 0; k < 12; ++k) t[k] = 0.f;
#pragma unroll
    for (int hh = 0; hh < 4; ++hh){
      const float* row = &tile[hh][tl][0];
      float4 c0 = *(const float4*)(row);
      float4 c1 = *(const float4*)(row + 4);
      float4 c2 = *(const float4*)(row + 8);
      t[0] += c0.x; t[1] += c0.y; t[2]  += c0.z; t[3]  += c0.w;
      t[4] += c1.x; t[5] += c1.y; t[6]  += c1.z; t[7]  += c1.w;
      t[8] += c2.x; t[9] += c2.y; t[10] += c2.z; t[11] += c2.w;
      sqv += row[16];
    }

    float mean = t[11] * (1.0f / D);
    float var  = fmaf(sqv, 1.0f / D, -mean * mean);
    float rr   = rsqrtf(var + 1e-5f);
    float u[NROW];
#pragma unroll
    for (int k = 0; k < NROW; ++k){
      float d = fmaf(-mean, a[k], t[k]);
      u[k] = tanh_fast(fmaf(rr, d, bb[k]));
    }

    // ---- Q2 ----
    float p01 = u[0] + u[1], m01 = u[0] - u[1];
    float l0 = -p01*it, l1 = -m01*it, l2 = m01*it, l3 = p01*it;
    float mx2 = fmaxf(fmaxf(l0, l1), fmaxf(l2, l3));
    float e0 = __expf(l0-mx2), e1 = __expf(l1-mx2), e2 = __expf(l2-mx2), e3 = __expf(l3-mx2);
    float i2 = rcp_fast(e0 + e1 + e2 + e3);
    float s2g0 = e3 * i2, s2g1 = (e1 + e2) * i2, s2g2 = e0 * i2;

    // ---- Q3 ----
    float l3v[8]; float mx3 = -1e30f;
#pragma unroll
    for (int v = 0; v < 8; ++v){
      float acc3 = ((v & 4) ? u[2] : -u[2]) + ((v & 2) ? u[3] : -u[3]) + ((v & 1) ? u[4] : -u[4]);
      l3v[v] = acc3 * it;
      mx3 = fmaxf(mx3, l3v[v]);
    }
    float w3v[8]; float se3 = 0.f;
#pragma unroll
    for (int v = 0; v < 8; ++v){ w3v[v] = __expf(l3v[v] - mx3); se3 += w3v[v]; }
    float i3 = rcp_fast(se3);
    float s3g0 = 0.f, s3g1 = 0.f, s3g2 = 0.f;
#pragma unroll
    for (int v = 0; v < 8; ++v){
      s3g0 = fmaf(w3v[v], M3r[v][0], s3g0);
      s3g1 = fmaf(w3v[v], M3r[v][1], s3g1);
      s3g2 = fmaf(w3v[v], M3r[v][2], s3g2);
    }
    s3g0 *= i3; s3g1 *= i3; s3g2 *= i3;

    // ---- Q6 (lane-parallel over 64 vertices) ----
    float lg = 0.f;
#pragma unroll
    for (int jj = 0; jj < 6; ++jj) lg = fmaf(sgn[jj], u[5 + jj], lg);
    lg *= it;
    float mx6 = wmax(lg);
    float p   = __expf(lg - mx6);
    float se6 = wsum(p);
    float hw  = p * rcp_fast(se6);
    hout[(size_t)tok * 64 + lane] = hw;
    hsum += hw;
    float s6g0 = wsum(hw * m60);
    float s6g1 = wsum(hw * m61);
    float s6g2 = wsum(hw * m62);

    // ---- combine + group softmax ----
    float g0 = mix0*s2g0 + mix1*s3g0 + mix2*s6g0;
    float g1 = mix0*s2g1 + mix1*s3g1 + mix2*s6g1;
    float g2 = mix0*s2g2 + mix1*s3g2 + mix2*s6g2;
    float gm = fmaxf(g0, fmaxf(g1, g2));
    float y0 = __expf(g0-gm), y1 = __expf(g1-gm), y2 = __expf(g2-gm);
    float gi = rcp_fast(y0 + y1 + y2);
    float gw0 = y0*gi, gw1 = y1*gi, gw2 = y2*gi;
    ga0 += gw0; ga1 += gw1; ga2 += gw2;
    if (lane < 3){
      float val = (lane == 0) ? gw0 : (lane == 1) ? gw1 : gw2;
      gout[(size_t)tok * 3 + lane] = val;
    }
  }

  // contention-free block partials for lb_loss
  lred[wid][lane] = hsum;
  if (lane < 3){
    float val = (lane == 0) ? ga0 : (lane == 1) ? ga1 : ga2;
    lred[wid][64 + lane] = val;
  }
  __syncthreads();
  if (tid < 67){
    float v = lred[0][tid] + lred[1][tid] + lred[2][tid] + lred[3][tid];
    part[(size_t)tid * K1_BLOCKS + blk] = v;
  }

  // ---- last-block election (device-scope fence + counter) ----
  __threadfence();            // release: publish part writes
  __syncthreads();
  if (tid == 0){
    unsigned int old = atomicAdd(ctr, 1u);
    if (old == K1_BLOCKS - 1){
      __threadfence();        // acquire: invalidate caches before reading parts
      is_last_s = 1u;
    } else {
      is_last_s = 0u;
    }
  }
  __syncthreads();
  if (!is_last_s) return;

  // ---- fused final reduction + lb_loss (runs on exactly one block) ----
  for (int jv = wid; jv < 67; jv += 4){
    const float4* p = (const float4*)(part + (size_t)jv * K1_BLOCKS);
    float v = 0.f;
#pragma unroll
    for (int b = 0; b < K1_BLOCKS / 256; ++b){
      float4 qq = p[lane + b * 64];
      v += (qq.x + qq.y) + (qq.z + qq.w);
    }
    v = wsum(v);
    if (lane == 0) sums[jv] = v;
  }
  __syncthreads();
  if (wid == 0){
    const float inv = 1.0f / (float)NTOK;
    float mh = sums[lane] * inv;
    float term = 0.1f * mh * logf(mh + 1e-8f);
    if (lane < 3){
      float mg = sums[64 + lane] * inv;
      term += mg * logf(mg + 1e-8f);
    }
    float L = wsum(term);
    if (lane == 0) lout[0] = L;
  }
}

extern "C" void kernel_launch(void* const* d_in, const int* in_sizes, int n_in,
                              void* d_out, int out_size, void* d_ws, size_t ws_size,
                              hipStream_t stream)
{
  const float* x             = (const float*)d_in[0];
  const float* ln_w          = (const float*)d_in[1];
  const float* ln_b          = (const float*)d_in[2];
  const float* w_q2          = (const float*)d_in[3];
  const float* w_q3          = (const float*)d_in[4];
  const float* w_q6          = (const float*)d_in[5];
  const float* log_temp      = (const float*)d_in[6];
  const float* log_scale_mix = (const float*)d_in[7];
  const float* q3_to_group   = (const float*)d_in[8];
  const float* log_wht_mix   = (const float*)d_in[9];

  float* out  = (float*)d_out;
  float* gout = out;                                        // (B,T,3)
  float* hout = out + (size_t)NTOK * 3;                     // (B,T,64)
  float* lout = out + (size_t)NTOK * 3 + (size_t)NTOK * 64; // scalar
  float* ws   = (float*)d_ws;
  unsigned int* ctr = (unsigned int*)ws + WS_CTR;

  k0_prep<<<12, 256, 0, stream>>>(ln_w, ln_b, w_q2, w_q3, w_q6,
                                  log_temp, log_scale_mix, q3_to_group, log_wht_mix, ws);
  k1_main<<<K1_BLOCKS, K1_THREADS, 0, stream>>>(x, ws, gout, hout,
                                                ws + WS_PART, ctr, lout);
}

// Round 21
// 46.356 us; speedup vs baseline: 3.3275x; 3.3238x over previous
//
#include <hip/hip_runtime.h>
#include <math.h>
#include <string.h>

#define D 2048
#define NTOK 16384
#define NROW 11
#define MROWS_U32 (NROW * D / 2)   // 11264 uints = 44 KB (packed 2xf16)
#define K1_BLOCKS 1024
#define K1_THREADS 256             // 4 waves; block = 16 tokens, wave = K-quarter
#define WSTRIDE_U 1036             // uints per LDS W row (4144 B; start banks 2-way = free)
#define TILE_S 20                  // f32 stride of C-tile row (80 B, 16B-aligned)

// ws layout (4-byte units):
// [0..10] a_k  [16..26] b_k  [32] inv_temp  [33] alpha  [34..36] mix
// [40..63] M3 (8x3)  [64 .. 64+11264) packed-f16 W'  [WS_PART..) partials [67][1024]
#define WS_A 0
#define WS_B 16
#define WS_IT 32
#define WS_ALPHA 33
#define WS_MIX 34
#define WS_M3 40
#define WS_MERGED 64
#define WS_PART (WS_MERGED + MROWS_U32)

typedef __fp16 h2 __attribute__((ext_vector_type(2)));
typedef __fp16 h8 __attribute__((ext_vector_type(8)));
typedef float f32x4 __attribute__((ext_vector_type(4)));

__device__ __forceinline__ float wsum(float v){
#pragma unroll
  for (int m = 1; m < 64; m <<= 1) v += __shfl_xor(v, m, 64);
  return v;
}
__device__ __forceinline__ float wmax(float v){
#pragma unroll
  for (int m = 1; m < 64; m <<= 1) v = fmaxf(v, __shfl_xor(v, m, 64));
  return v;
}
__device__ __forceinline__ float rcp_fast(float x){ return __builtin_amdgcn_rcpf(x); }
__device__ __forceinline__ float tanh_fast(float x){
  float e = __expf(2.0f * x);
  return 1.0f - 2.0f * rcp_fast(e + 1.0f);
}
__device__ __forceinline__ float sload(const float* __restrict__ p){
  return __uint_as_float(__builtin_amdgcn_readfirstlane(__float_as_uint(*p)));
}
__device__ __forceinline__ unsigned int h2u(h2 h){ unsigned int u; memcpy(&u, &h, 4); return u; }

// ---------------- k0: merge rows (f16-packed) + constants (12 blocks) ----------------
__global__ __launch_bounds__(256) void k0_prep(
    const float* __restrict__ ln_w, const float* __restrict__ ln_b,
    const float* __restrict__ w_q2, const float* __restrict__ w_q3,
    const float* __restrict__ w_q6,
    const float* __restrict__ log_temp, const float* __restrict__ log_scale_mix,
    const float* __restrict__ q3_to_group, const float* __restrict__ log_wht_mix,
    float* __restrict__ ws)
{
  const int tid = threadIdx.x;
  const int k = blockIdx.x;
  unsigned int* wsu = (unsigned int*)ws;
  if (k < NROW){
    const float* row = (k < 2) ? (w_q2 + (size_t)k * D)
                     : (k < 5) ? (w_q3 + (size_t)(k - 2) * D)
                               : (w_q6 + (size_t)(k - 5) * D);
    float pa = 0.f, pb = 0.f;
    for (int i = tid * 2; i < D; i += 512){
      float w0 = row[i], w1 = row[i + 1];
      h2 h = __builtin_amdgcn_cvt_pkrtz(ln_w[i] * w0, ln_w[i + 1] * w1);
      pa += (float)h[0] + (float)h[1];          // a_k from ROUNDED values
      pb = fmaf(ln_b[i], w0, pb);
      pb = fmaf(ln_b[i + 1], w1, pb);
      wsu[WS_MERGED + k * 1024 + i / 2] = h2u(h);
    }
    __shared__ float red[8];
    pa = wsum(pa); pb = wsum(pb);
    if ((tid & 63) == 0){ red[tid >> 6] = pa; red[4 + (tid >> 6)] = pb; }
    __syncthreads();
    if (tid == 0){
      ws[WS_A + k] = red[0] + red[1] + red[2] + red[3];
      ws[WS_B + k] = red[4] + red[5] + red[6] + red[7];
    }
  } else if (tid < 64){
    // block 11: constants, lane-parallel
    const int lane = tid;
    float q3v = (lane < 24) ? q3_to_group[lane]   : 0.f;
    float sc  = (lane < 3)  ? log_scale_mix[lane] : 0.f;
    float lt  = (lane == 0) ? log_temp[0]         : 0.f;
    float lw  = (lane == 0) ? log_wht_mix[0]      : 0.f;

    if (lane == 0){
      float t = __expf(lt);
      t = fminf(fmaxf(t, 0.1f), 5.0f);
      ws[WS_IT] = 1.0f / t;
      ws[WS_ALPHA] = 1.0f / (1.0f + __expf(-lw));
    }
    float m0 = __shfl(sc, 0, 64), m1 = __shfl(sc, 1, 64), m2 = __shfl(sc, 2, 64);
    if (lane < 3){
      float mm = fmaxf(m0, fmaxf(m1, m2));
      float e0 = __expf(m0 - mm), e1 = __expf(m1 - mm), e2 = __expf(m2 - mm);
      float inv = 1.0f / (e0 + e1 + e2);
      ws[WS_MIX + lane] = ((lane == 0) ? e0 : (lane == 1) ? e1 : e2) * inv;
    }
    if (lane < 24){
      int r = lane / 3, c = lane - r * 3;
      float v0 = __shfl(q3v, r*3 + 0, 64);
      float v1 = __shfl(q3v, r*3 + 1, 64);
      float v2 = __shfl(q3v, r*3 + 2, 64);
      float mx = fmaxf(v0, fmaxf(v1, v2));
      float f0 = __expf(v0 - mx), f1 = __expf(v1 - mx), f2 = __expf(v2 - mx);
      float iv = 1.0f / (f0 + f1 + f2);
      ws[WS_M3 + lane] = ((c == 0) ? f0 : (c == 1) ? f1 : f2) * iv;
    }
  }
}

// ---------------- k1: MFMA per-token kernel ----------------
// 1024 blocks x 256 threads (4 waves). Block = 16 tokens, wave = K-quarter:
// 16x v_mfma_f32_16x16x32_f16 into a 16x16 C tile. Batch-2 x loads issued
// AFTER the barrier so K-loop part 1 MFMAs cover their latency. Epilogue is
// fully unrolled so the 4 tokens' shuffle-reduction chains interleave.
__global__ __launch_bounds__(256) void k1_main(
    const float* __restrict__ x, const float* __restrict__ ws,
    float* __restrict__ gout, float* __restrict__ hout, float* __restrict__ part)
{
  __shared__ unsigned int sW[NROW * WSTRIDE_U];    // 45.6 KB
  __shared__ float tile[4][16][TILE_S];            // 5.1 KB
  __shared__ float lred[4][68];
  const int tid  = threadIdx.x;
  const int lane = tid & 63;
  const int wid  = tid >> 6;          // K-quarter
  const int blk  = blockIdx.x;
  const int tok0 = blk * 16;
  const int n = lane & 15;            // A-row (token) / B-col (W row)
  const int q = lane >> 4;            // K-chunk within step

  const float* xp = x + (size_t)(tok0 + n) * D + wid * 512 + q * 8;

  // ---- issue batch-1 loads (steps 0..7) ----
  float4 xa[16];
#pragma unroll
  for (int s = 0; s < 8; ++s){
    xa[2*s]     = *(const float4*)(xp + s * 32);
    xa[2*s + 1] = *(const float4*)(xp + s * 32 + 4);
  }

  // ---- stage W' (11 rows, stride 1036 u) -- covers batch-1 latency ----
  {
    const uint4* src = (const uint4*)((const unsigned int*)ws + WS_MERGED);
#pragma unroll
    for (int j = 0; j < 11; ++j){
      int idx = tid + j * 256;
      int r = idx >> 8, i = idx & 255;
      *(uint4*)(sW + r * WSTRIDE_U + i * 4) = src[r * 256 + i];
    }
  }

  // ---- convert batch 1 -> h8 frags + sq ----
  float sq = 0.f;
  h8 hxA[8], hxB[8];
#pragma unroll
  for (int s = 0; s < 8; ++s){
    float4 f0 = xa[2*s], f1 = xa[2*s + 1];
    sq = fmaf(f0.x,f0.x, fmaf(f0.y,f0.y, fmaf(f0.z,f0.z, fmaf(f0.w,f0.w, sq))));
    sq = fmaf(f1.x,f1.x, fmaf(f1.y,f1.y, fmaf(f1.z,f1.z, fmaf(f1.w,f1.w, sq))));
    h2 p0 = __builtin_amdgcn_cvt_pkrtz(f0.x, f0.y);
    h2 p1 = __builtin_amdgcn_cvt_pkrtz(f0.z, f0.w);
    h2 p2 = __builtin_amdgcn_cvt_pkrtz(f1.x, f1.y);
    h2 p3 = __builtin_amdgcn_cvt_pkrtz(f1.z, f1.w);
    h8 A;
    A[0]=p0[0]; A[1]=p0[1]; A[2]=p1[0]; A[3]=p1[1];
    A[4]=p2[0]; A[5]=p2[1]; A[6]=p3[0]; A[7]=p3[1];
    hxA[s] = A;
  }

  __syncthreads();   // W' staged

  // ---- issue batch-2 loads AFTER barrier: K-loop part 1 covers latency ----
#pragma unroll
  for (int s = 0; s < 8; ++s){
    xa[2*s]     = *(const float4*)(xp + (s + 8) * 32);
    xa[2*s + 1] = *(const float4*)(xp + (s + 8) * 32 + 4);
  }

  const int wr = (n < NROW) ? n : (n - NROW);
  const bool is_ones = (n == NROW);
  const uint4 ones4 = make_uint4(0x3C003C00u, 0x3C003C00u, 0x3C003C00u, 0x3C003C00u);
  const unsigned int* wb = sW + wr * WSTRIDE_U + wid * 256 + q * 4;

  f32x4 acc = {0.f, 0.f, 0.f, 0.f};

#pragma unroll
  for (int s = 0; s < 8; ++s){
    uint4 wq = *(const uint4*)(wb + s * 16);
    if (is_ones) wq = ones4;
    h8 B; memcpy(&B, &wq, 16);
    acc = __builtin_amdgcn_mfma_f32_16x16x32_f16(hxA[s], B, acc, 0, 0, 0);
  }

#pragma unroll
  for (int s = 0; s < 8; ++s){
    float4 f0 = xa[2*s], f1 = xa[2*s + 1];
    sq = fmaf(f0.x,f0.x, fmaf(f0.y,f0.y, fmaf(f0.z,f0.z, fmaf(f0.w,f0.w, sq))));
    sq = fmaf(f1.x,f1.x, fmaf(f1.y,f1.y, fmaf(f1.z,f1.z, fmaf(f1.w,f1.w, sq))));
    h2 p0 = __builtin_amdgcn_cvt_pkrtz(f0.x, f0.y);
    h2 p1 = __builtin_amdgcn_cvt_pkrtz(f0.z, f0.w);
    h2 p2 = __builtin_amdgcn_cvt_pkrtz(f1.x, f1.y);
    h2 p3 = __builtin_amdgcn_cvt_pkrtz(f1.z, f1.w);
    h8 A;
    A[0]=p0[0]; A[1]=p0[1]; A[2]=p1[0]; A[3]=p1[1];
    A[4]=p2[0]; A[5]=p2[1]; A[6]=p3[0]; A[7]=p3[1];
    hxB[s] = A;
  }

#pragma unroll
  for (int s = 0; s < 8; ++s){
    uint4 wq = *(const uint4*)(wb + (s + 8) * 16);
    if (is_ones) wq = ones4;
    h8 B; memcpy(&B, &wq, 16);
    acc = __builtin_amdgcn_mfma_f32_16x16x32_f16(hxB[s], B, acc, 0, 0, 0);
  }

  // sq: reduce over the 4 K-chunk lanes of token n
  sq += __shfl_xor(sq, 16, 64);
  sq += __shfl_xor(sq, 32, 64);

  // C layout (m89): token = q*4 + r, output col = n
#pragma unroll
  for (int r = 0; r < 4; ++r) tile[wid][q * 4 + r][n] = acc[r];
  if (lane < 16) tile[wid][lane][16] = sq;

  __syncthreads();

  // uniform constants -> SGPRs
  float a[NROW], bb[NROW];
#pragma unroll
  for (int k = 0; k < NROW; ++k){ a[k] = sload(ws + WS_A + k); bb[k] = sload(ws + WS_B + k); }
  const float it    = sload(ws + WS_IT);
  const float alpha = sload(ws + WS_ALPHA);
  const float mix0 = sload(ws + WS_MIX), mix1 = sload(ws + WS_MIX + 1), mix2 = sload(ws + WS_MIX + 2);
  float M3r[8][3];
#pragma unroll
  for (int r = 0; r < 8; ++r){
#pragma unroll
    for (int g2 = 0; g2 < 3; ++g2) M3r[r][g2] = sload(ws + WS_M3 + r*3 + g2);
  }

  // per-lane hexagram row constants
  float sgn[6];
#pragma unroll
  for (int j = 0; j < 6; ++j) sgn[j] = ((lane >> (5 - j)) & 1) ? 1.0f : -1.0f;
  const float C5 = 0.44721359549995793f; // 1/sqrt(5)
  const float A0c[6] = { C5,  C5,  C5,  C5,  C5, 0.f };
  const float A1c[6] = {-0.5f, 0.5f, -0.5f, 0.f, 0.f, 0.5f};
  const float A2c[6] = {-C5, -C5, 0.f, -C5, -C5, -C5};
  float cs0 = 0.f, cs1 = 0.f, cs2 = 0.f;
#pragma unroll
  for (int j = 0; j < 6; ++j){
    cs0 = fmaf(sgn[j], A0c[j], cs0);
    cs1 = fmaf(sgn[j], A1c[j], cs1);
    cs2 = fmaf(sgn[j], A2c[j], cs2);
  }
  const int pc = __popc(lane);
  const float w7c = 1.0f / 7.0f;
  float wh0 = (pc >= 5) ? w7c  : 0.f;
  float wh1 = (pc == 3) ? 0.05f: 0.f;
  float wh2 = (pc <= 1) ? w7c  : 0.f;
  const float m60 = (1.f - alpha)*cs0 + alpha*wh0;
  const float m61 = (1.f - alpha)*cs1 + alpha*wh1;
  const float m62 = (1.f - alpha)*cs2 + alpha*wh2;

  float hsum = 0.f, ga0 = 0.f, ga1 = 0.f, ga2 = 0.f;

  // epilogue: wave wid handles local tokens wid*4 .. wid*4+3, fully unrolled
#pragma unroll
  for (int i = 0; i < 4; ++i){
    const int tl  = wid * 4 + i;
    const int tok = tok0 + tl;

    float t[12]; float sqv = 0.f;
#pragma unroll
    for (int k = 0; k < 12; ++k) t[k] = 0.f;
#pragma unroll
    for (int hh = 0; hh < 4; ++hh){
      const float* row = &tile[hh][tl][0];
      float4 c0 = *(const float4*)(row);
      float4 c1 = *(const float4*)(row + 4);
      float4 c2 = *(const float4*)(row + 8);
      t[0] += c0.x; t[1] += c0.y; t[2]  += c0.z; t[3]  += c0.w;
      t[4] += c1.x; t[5] += c1.y; t[6]  += c1.z; t[7]  += c1.w;
      t[8] += c2.x; t[9] += c2.y; t[10] += c2.z; t[11] += c2.w;
      sqv += row[16];
    }

    float mean = t[11] * (1.0f / D);
    float var  = fmaf(sqv, 1.0f / D, -mean * mean);
    float rr   = rsqrtf(var + 1e-5f);
    float u[NROW];
#pragma unroll
    for (int k = 0; k < NROW; ++k){
      float d = fmaf(-mean, a[k], t[k]);
      u[k] = tanh_fast(fmaf(rr, d, bb[k]));
    }

    // ---- Q2 ----
    float p01 = u[0] + u[1], m01 = u[0] - u[1];
    float l0 = -p01*it, l1 = -m01*it, l2 = m01*it, l3 = p01*it;
    float mx2 = fmaxf(fmaxf(l0, l1), fmaxf(l2, l3));
    float e0 = __expf(l0-mx2), e1 = __expf(l1-mx2), e2 = __expf(l2-mx2), e3 = __expf(l3-mx2);
    float i2 = rcp_fast(e0 + e1 + e2 + e3);
    float s2g0 = e3 * i2, s2g1 = (e1 + e2) * i2, s2g2 = e0 * i2;

    // ---- Q3 ----
    float l3v[8]; float mx3 = -1e30f;
#pragma unroll
    for (int v = 0; v < 8; ++v){
      float acc3 = ((v & 4) ? u[2] : -u[2]) + ((v & 2) ? u[3] : -u[3]) + ((v & 1) ? u[4] : -u[4]);
      l3v[v] = acc3 * it;
      mx3 = fmaxf(mx3, l3v[v]);
    }
    float w3v[8]; float se3 = 0.f;
#pragma unroll
    for (int v = 0; v < 8; ++v){ w3v[v] = __expf(l3v[v] - mx3); se3 += w3v[v]; }
    float i3 = rcp_fast(se3);
    float s3g0 = 0.f, s3g1 = 0.f, s3g2 = 0.f;
#pragma unroll
    for (int v = 0; v < 8; ++v){
      s3g0 = fmaf(w3v[v], M3r[v][0], s3g0);
      s3g1 = fmaf(w3v[v], M3r[v][1], s3g1);
      s3g2 = fmaf(w3v[v], M3r[v][2], s3g2);
    }
    s3g0 *= i3; s3g1 *= i3; s3g2 *= i3;

    // ---- Q6 (lane-parallel over 64 vertices) ----
    float lg = 0.f;
#pragma unroll
    for (int jj = 0; jj < 6; ++jj) lg = fmaf(sgn[jj], u[5 + jj], lg);
    lg *= it;
    float mx6 = wmax(lg);
    float p   = __expf(lg - mx6);
    float se6 = wsum(p);
    float hw  = p * rcp_fast(se6);
    hout[(size_t)tok * 64 + lane] = hw;
    hsum += hw;
    float s6g0 = wsum(hw * m60);
    float s6g1 = wsum(hw * m61);
    float s6g2 = wsum(hw * m62);

    // ---- combine + group softmax ----
    float g0 = mix0*s2g0 + mix1*s3g0 + mix2*s6g0;
    float g1 = mix0*s2g1 + mix1*s3g1 + mix2*s6g1;
    float g2 = mix0*s2g2 + mix1*s3g2 + mix2*s6g2;
    float gm = fmaxf(g0, fmaxf(g1, g2));
    float y0 = __expf(g0-gm), y1 = __expf(g1-gm), y2 = __expf(g2-gm);
    float gi = rcp_fast(y0 + y1 + y2);
    float gw0 = y0*gi, gw1 = y1*gi, gw2 = y2*gi;
    ga0 += gw0; ga1 += gw1; ga2 += gw2;
    if (lane < 3){
      float val = (lane == 0) ? gw0 : (lane == 1) ? gw1 : gw2;
      gout[(size_t)tok * 3 + lane] = val;
    }
  }

  // contention-free block partials for lb_loss
  lred[wid][lane] = hsum;
  if (lane < 3){
    float val = (lane == 0) ? ga0 : (lane == 1) ? ga1 : ga2;
    lred[wid][64 + lane] = val;
  }
  __syncthreads();
  if (tid < 67){
    float v = lred[0][tid] + lred[1][tid] + lred[2][tid] + lred[3][tid];
    part[(size_t)tid * K1_BLOCKS + blk] = v;
  }
}

// ---------------- k2: final reduction + lb_loss ----------------
__global__ __launch_bounds__(1024) void k2_loss(const float* __restrict__ part,
                                                float* __restrict__ lout)
{
  __shared__ float sums[68];
  const int tid = threadIdx.x;
  const int lane = tid & 63;
  const int wid  = tid >> 6;
  for (int jv = wid; jv < 67; jv += 16){
    const float4* p = (const float4*)(part + (size_t)jv * K1_BLOCKS);
    float v = 0.f;
#pragma unroll
    for (int b = 0; b < K1_BLOCKS / 256; ++b){
      float4 q = p[lane + b * 64];
      v += (q.x + q.y) + (q.z + q.w);
    }
    v = wsum(v);
    if (lane == 0) sums[jv] = v;
  }
  __syncthreads();
  if (wid == 0){
    const float inv = 1.0f / (float)NTOK;
    float mh = sums[lane] * inv;
    float term = 0.1f * mh * logf(mh + 1e-8f);
    if (lane < 3){
      float mg = sums[64 + lane] * inv;
      term += mg * logf(mg + 1e-8f);
    }
    float L = wsum(term);
    if (lane == 0) lout[0] = L;
  }
}

extern "C" void kernel_launch(void* const* d_in, const int* in_sizes, int n_in,
                              void* d_out, int out_size, void* d_ws, size_t ws_size,
                              hipStream_t stream)
{
  const float* x             = (const float*)d_in[0];
  const float* ln_w          = (const float*)d_in[1];
  const float* ln_b          = (const float*)d_in[2];
  const float* w_q2          = (const float*)d_in[3];
  const float* w_q3          = (const float*)d_in[4];
  const float* w_q6          = (const float*)d_in[5];
  const float* log_temp      = (const float*)d_in[6];
  const float* log_scale_mix = (const float*)d_in[7];
  const float* q3_to_group   = (const float*)d_in[8];
  const float* log_wht_mix   = (const float*)d_in[9];

  float* out  = (float*)d_out;
  float* gout = out;                                        // (B,T,3)
  float* hout = out + (size_t)NTOK * 3;                     // (B,T,64)
  float* lout = out + (size_t)NTOK * 3 + (size_t)NTOK * 64; // scalar
  float* ws   = (float*)d_ws;

  k0_prep<<<12, 256, 0, stream>>>(ln_w, ln_b, w_q2, w_q3, w_q6,
                                  log_temp, log_scale_mix, q3_to_group, log_wht_mix, ws);
  k1_main<<<K1_BLOCKS, K1_THREADS, 0, stream>>>(x, ws, gout, hout, ws + WS_PART);
  k2_loss<<<1, 1024, 0, stream>>>(ws + WS_PART, lout);
}